// Round 17
// baseline (1124.002 us; speedup 1.0000x reference)
//
#include <hip/hip_runtime.h>
#include <hip/hip_bf16.h>

typedef unsigned short u16;
typedef unsigned int u32;
typedef __attribute__((ext_vector_type(8))) __bf16 bf16x8;
typedef __attribute__((ext_vector_type(4))) float f32x4;
typedef __attribute__((ext_vector_type(4))) u16 u16x4;
typedef __attribute__((ext_vector_type(8))) u16 u16x8;

#define SCUR 4096
#define SMEM 16384
#define DM   256
#define DFFN 2048
#define NL   4

__device__ __forceinline__ u16 f2b(float f){
  u32 i; __builtin_memcpy(&i, &f, 4);
  u32 r = (i + 0x7fffu + ((i >> 16) & 1u)) >> 16;
  return (u16)r;
}
__device__ __forceinline__ float b2f(u16 v){
  u32 i = ((u32)v) << 16; float f; __builtin_memcpy(&f, &i, 4); return f;
}

__device__ __forceinline__ f32x4 mfma16(bf16x8 a, bf16x8 b, f32x4 c){
  return __builtin_amdgcn_mfma_f32_16x16x32_bf16(a, b, c, 0, 0, 0);
}

__device__ __forceinline__ void glds16(const u16* g, u16* l){
  __builtin_amdgcn_global_load_lds(
      (const __attribute__((address_space(1))) u32*)g,
      (__attribute__((address_space(3))) u32*)l, 16, 0, 0);
}

// ---------------- elementwise prep ----------------

__global__ void axpy_k(const float* __restrict__ a, const float* __restrict__ b,
                       float s, float* __restrict__ o, int n4){
  int i = blockIdx.x * blockDim.x + threadIdx.x;
  int st = gridDim.x * blockDim.x;
  for (; i < n4; i += st){
    float4 x = ((const float4*)a)[i];
    float4 y = ((const float4*)b)[i];
    float4 r; r.x = x.x + s*y.x; r.y = x.y + s*y.y; r.z = x.z + s*y.z; r.w = x.w + s*y.w;
    ((float4*)o)[i] = r;
  }
}

__global__ void cvt_bf16_k(const float* __restrict__ a, const float* __restrict__ b,
                           u16* __restrict__ o, int n4, float s){
  int i = blockIdx.x * blockDim.x + threadIdx.x;
  int st = gridDim.x * blockDim.x;
  const bool hb = (b != nullptr);
  for (; i < n4; i += st){
    float4 x = ((const float4*)a)[i];
    if (hb){
      float4 y = ((const float4*)b)[i];
      x.x += s*y.x; x.y += s*y.y; x.z += s*y.z; x.w += s*y.w;
    }
    u16x4 r = { f2b(x.x), f2b(x.y), f2b(x.z), f2b(x.w) };
    ((u16x4*)o)[i] = r;
  }
}

// ---------------- layernorm ----------------
template<int OUTF32>
__global__ __launch_bounds__(256) void ln_k(const float* __restrict__ X,
    const float* __restrict__ g, const float* __restrict__ b,
    void* __restrict__ out, int rows){
  int row = blockIdx.x * 4 + (threadIdx.x >> 6);
  int lane = threadIdx.x & 63;
  if (row >= rows) return;
  const float4 v = *(const float4*)(X + (size_t)row*DM + lane*4);
  float s = v.x + v.y + v.z + v.w;
  for (int off = 1; off < 64; off <<= 1) s += __shfl_xor(s, off, 64);
  float mu = s * (1.f/256.f);
  float dx = v.x-mu, dy = v.y-mu, dz = v.z-mu, dw = v.w-mu;
  float q = dx*dx + dy*dy + dz*dz + dw*dw;
  for (int off = 1; off < 64; off <<= 1) q += __shfl_xor(q, off, 64);
  float rstd = rsqrtf(q * (1.f/256.f) + 1e-5f);
  const float4 gw = *(const float4*)(g + lane*4);
  const float4 gb = *(const float4*)(b + lane*4);
  float y0 = dx*rstd*gw.x + gb.x;
  float y1 = dy*rstd*gw.y + gb.y;
  float y2 = dz*rstd*gw.z + gb.z;
  float y3 = dw*rstd*gw.w + gb.w;
  if (OUTF32){
    float4 o; o.x=y0; o.y=y1; o.z=y2; o.w=y3;
    *(float4*)((float*)out + (size_t)row*DM + lane*4) = o;
  } else {
    u16x4 o = { f2b(y0), f2b(y1), f2b(y2), f2b(y3) };
    *(u16x4*)((u16*)out + (size_t)row*DM + lane*4) = o;
  }
}

// ---------------- 64-tile GEMM (small grids) ----------------
template<int EPI>
__global__ __launch_bounds__(256) void gemm_bt(
    const u16* __restrict__ A, int lda, const u16* __restrict__ W, int ldw,
    const float* __restrict__ bias, void* __restrict__ out, int ldc,
    int M, int N, int K){
  __shared__ u16 a_sm[64*40];
  __shared__ u16 b_sm[64*40];
  const int tid = threadIdx.x;
  const int lane = tid & 63;
  const int w = tid >> 6;
  const int l16 = lane & 15, lg = lane >> 4;
  const int m0 = blockIdx.y * 64;
  const int n0 = blockIdx.x * 64;
  const int wr = (w >> 1) * 32, wc = (w & 1) * 32;
  f32x4 acc[2][2] = {};
  const int srow = tid >> 2, sch = tid & 3;
  const u16* Ag = A + (size_t)(m0 + srow) * lda + sch * 8;
  const u16* Wg = W + (size_t)(n0 + srow) * ldw + sch * 8;
  u16x8 av = *(const u16x8*)(Ag);
  u16x8 wv = *(const u16x8*)(Wg);
  for (int k0 = 0; k0 < K; k0 += 32){
    __syncthreads();
    *(u16x8*)(a_sm + srow*40 + sch*8) = av;
    *(u16x8*)(b_sm + srow*40 + sch*8) = wv;
    if (k0 + 32 < K){
      av = *(const u16x8*)(Ag + k0 + 32);
      wv = *(const u16x8*)(Wg + k0 + 32);
    }
    __syncthreads();
    bf16x8 af0 = *(const bf16x8*)(a_sm + (wr      + l16)*40 + lg*8);
    bf16x8 af1 = *(const bf16x8*)(a_sm + (wr + 16 + l16)*40 + lg*8);
    bf16x8 bf0 = *(const bf16x8*)(b_sm + (wc      + l16)*40 + lg*8);
    bf16x8 bf1 = *(const bf16x8*)(b_sm + (wc + 16 + l16)*40 + lg*8);
    acc[0][0] = mfma16(af0, bf0, acc[0][0]);
    acc[0][1] = mfma16(af0, bf1, acc[0][1]);
    acc[1][0] = mfma16(af1, bf0, acc[1][0]);
    acc[1][1] = mfma16(af1, bf1, acc[1][1]);
  }
  for (int mi = 0; mi < 2; mi++)
    for (int ni = 0; ni < 2; ni++)
      for (int r = 0; r < 4; r++){
        int m = m0 + wr + mi*16 + lg*4 + r;
        int n = n0 + wc + ni*16 + l16;
        float v = acc[mi][ni][r];
        if (EPI == 3)      v += bias[m];
        else if (EPI != 4) v += bias[n];
        if (EPI == 2)      ((float*)out)[(size_t)m*ldc + n] += v;
        else if (EPI == 1) ((u16*)out)[(size_t)m*ldc + n] = f2b(v > 0.f ? v : 0.f);
        else               ((u16*)out)[(size_t)m*ldc + n] = f2b(v);
      }
}

// ---------------- 128x128-tile GEMM, double-buffered + counted vmcnt ----------------
// EPI: 1 relu->bf16+bias[n], 4 bf16 no bias,
//      6 p=exp(acc*scale)->bf16 + per-row l-partials (lpart[(bx*2+(w&1))][m])
template<int EPI>
__global__ void gemm128(
    const u16* __restrict__ A, int lda, const u16* __restrict__ W, int ldw,
    const float* __restrict__ bias, void* __restrict__ out, int ldc,
    int M, int N, int K, float scale, float* __restrict__ lpart){
  __shared__ u16 a_sm[2][128*32];
  __shared__ u16 b_sm[2][128*32];
  const int tid = threadIdx.x, lane = tid & 63, w = tid >> 6;
  const int l16 = lane & 15, lg = lane >> 4;
  const int m0 = blockIdx.y * 128, n0 = blockIdx.x * 128;
  const int wr = (w >> 1) * 64, wc = (w & 1) * 64;
  f32x4 acc[4][4] = {};
  const int c0 = w*64 + lane, c1 = c0 + 256;
  const int r0 = c0 >> 2, cc0 = c0 & 3;
  const int r1 = c1 >> 2, cc1 = c1 & 3;
  const u16* Ag0 = A + (size_t)(m0 + r0)*lda + cc0*8;
  const u16* Ag1 = A + (size_t)(m0 + r1)*lda + cc1*8;
  const u16* Wg0 = W + (size_t)(n0 + r0)*ldw + cc0*8;
  const u16* Wg1 = W + (size_t)(n0 + r1)*ldw + cc1*8;
  const int nk = K >> 5;
  glds16(Ag0, a_sm[0] + w*512);
  glds16(Ag1, a_sm[0] + w*512 + 2048);
  glds16(Wg0, b_sm[0] + w*512);
  glds16(Wg1, b_sm[0] + w*512 + 2048);
  __builtin_amdgcn_sched_barrier(0);
  for (int k = 0; k < nk; k++){
    const int cur = k & 1;
    if (k + 1 < nk){
      const int nxt = cur ^ 1;
      const int ko = (k + 1) * 32;
      glds16(Ag0 + ko, a_sm[nxt] + w*512);
      glds16(Ag1 + ko, a_sm[nxt] + w*512 + 2048);
      glds16(Wg0 + ko, b_sm[nxt] + w*512);
      glds16(Wg1 + ko, b_sm[nxt] + w*512 + 2048);
      __builtin_amdgcn_sched_barrier(0);
      asm volatile("s_waitcnt vmcnt(4)" ::: "memory");
    } else {
      asm volatile("s_waitcnt vmcnt(0)" ::: "memory");
    }
    __builtin_amdgcn_s_barrier();
    bf16x8 af[4], bf[4];
    #pragma unroll
    for (int mi = 0; mi < 4; mi++)
      af[mi] = *(const bf16x8*)(a_sm[cur] + (wr + mi*16 + l16)*32 + lg*8);
    #pragma unroll
    for (int ni = 0; ni < 4; ni++)
      bf[ni] = *(const bf16x8*)(b_sm[cur] + (wc + ni*16 + l16)*32 + lg*8);
    #pragma unroll
    for (int mi = 0; mi < 4; mi++)
      #pragma unroll
      for (int ni = 0; ni < 4; ni++)
        acc[mi][ni] = mfma16(af[mi], bf[ni], acc[mi][ni]);
    __builtin_amdgcn_s_barrier();
  }
  if (EPI == 6){
    #pragma unroll
    for (int mi = 0; mi < 4; mi++)
      #pragma unroll
      for (int r = 0; r < 4; r++){
        float ls = 0.f;
        #pragma unroll
        for (int ni = 0; ni < 4; ni++){
          float p = __expf(acc[mi][ni][r] * scale);
          acc[mi][ni][r] = p;
          ls += p;
        }
        #pragma unroll
        for (int off = 1; off < 16; off <<= 1) ls += __shfl_xor(ls, off, 64);
        if (l16 == 0){
          int m = m0 + wr + mi*16 + lg*4 + r;
          lpart[(size_t)(blockIdx.x*2 + (w & 1)) * M + m] = ls;
        }
      }
  }
  #pragma unroll
  for (int mi = 0; mi < 4; mi++)
    #pragma unroll
    for (int ni = 0; ni < 4; ni++)
      #pragma unroll
      for (int r = 0; r < 4; r++){
        int m = m0 + wr + mi*16 + lg*4 + r;
        int n = n0 + wc + ni*16 + l16;
        float v = acc[mi][ni][r];
        if (EPI == 1){
          v += bias[n];
          ((u16*)out)[(size_t)m*ldc + n] = f2b(v > 0.f ? v : 0.f);
        } else {
          ((u16*)out)[(size_t)m*ldc + n] = f2b(v);
        }
      }
}

// ---------------- wide-N GEMM for PV / down-proj (BM=64, N=256, 2-deep prefetch) ----------------
// Plain streaming (no per-element transform). K divisible by 64.
__global__ __launch_bounds__(256) void gemm_pv(
    const u16* __restrict__ A, int lda, const u16* __restrict__ W, int ldw,
    u16* __restrict__ out, int M, int K){
  __shared__ u16 a_sm[64*40];
  __shared__ u16 b_sm[256*40];
  const int tid = threadIdx.x, lane = tid & 63, w = tid >> 6;
  const int l16 = lane & 15, lg = lane >> 4;
  const int m0 = blockIdx.x * 64;
  const int koff = blockIdx.y * K;
  f32x4 acc[4][4] = {};
  const int srow = tid >> 2, sch = tid & 3;
  const u16* Ag = A + (size_t)(m0 + srow) * lda + sch * 8 + koff;
  const u16* Wg = W + (size_t)srow * ldw + sch * 8 + koff;
  u16x8 avX = *(const u16x8*)(Ag);
  u16x8 wv0X = *(const u16x8*)(Wg);
  u16x8 wv1X = *(const u16x8*)(Wg + (size_t)64*ldw);
  u16x8 wv2X = *(const u16x8*)(Wg + (size_t)128*ldw);
  u16x8 wv3X = *(const u16x8*)(Wg + (size_t)192*ldw);
  u16x8 avY = *(const u16x8*)(Ag + 32);
  u16x8 wv0Y = *(const u16x8*)(Wg + 32);
  u16x8 wv1Y = *(const u16x8*)(Wg + (size_t)64*ldw + 32);
  u16x8 wv2Y = *(const u16x8*)(Wg + (size_t)128*ldw + 32);
  u16x8 wv3Y = *(const u16x8*)(Wg + (size_t)192*ldw + 32);
  for (int k0 = 0; k0 < K; k0 += 64){
    __syncthreads();
    *(u16x8*)(a_sm + srow*40 + sch*8) = avX;
    *(u16x8*)(b_sm + srow*40 + sch*8) = wv0X;
    *(u16x8*)(b_sm + (srow+64)*40 + sch*8) = wv1X;
    *(u16x8*)(b_sm + (srow+128)*40 + sch*8) = wv2X;
    *(u16x8*)(b_sm + (srow+192)*40 + sch*8) = wv3X;
    if (k0 + 64 < K){
      avX  = *(const u16x8*)(Ag + k0 + 64);
      wv0X = *(const u16x8*)(Wg + k0 + 64);
      wv1X = *(const u16x8*)(Wg + (size_t)64*ldw + k0 + 64);
      wv2X = *(const u16x8*)(Wg + (size_t)128*ldw + k0 + 64);
      wv3X = *(const u16x8*)(Wg + (size_t)192*ldw + k0 + 64);
    }
    __syncthreads();
    {
      bf16x8 af[4], bf[4];
      #pragma unroll
      for (int i = 0; i < 4; i++)
        af[i] = *(const bf16x8*)(a_sm + (i*16 + l16)*40 + lg*8);
      #pragma unroll
      for (int i = 0; i < 4; i++)
        bf[i] = *(const bf16x8*)(b_sm + (w*64 + i*16 + l16)*40 + lg*8);
      #pragma unroll
      for (int mi = 0; mi < 4; mi++)
        #pragma unroll
        for (int ni = 0; ni < 4; ni++)
          acc[mi][ni] = mfma16(af[mi], bf[ni], acc[mi][ni]);
    }
    __syncthreads();
    *(u16x8*)(a_sm + srow*40 + sch*8) = avY;
    *(u16x8*)(b_sm + srow*40 + sch*8) = wv0Y;
    *(u16x8*)(b_sm + (srow+64)*40 + sch*8) = wv1Y;
    *(u16x8*)(b_sm + (srow+128)*40 + sch*8) = wv2Y;
    *(u16x8*)(b_sm + (srow+192)*40 + sch*8) = wv3Y;
    if (k0 + 96 < K){
      avY  = *(const u16x8*)(Ag + k0 + 96);
      wv0Y = *(const u16x8*)(Wg + k0 + 96);
      wv1Y = *(const u16x8*)(Wg + (size_t)64*ldw + k0 + 96);
      wv2Y = *(const u16x8*)(Wg + (size_t)128*ldw + k0 + 96);
      wv3Y = *(const u16x8*)(Wg + (size_t)192*ldw + k0 + 96);
    }
    __syncthreads();
    {
      bf16x8 af[4], bf[4];
      #pragma unroll
      for (int i = 0; i < 4; i++)
        af[i] = *(const bf16x8*)(a_sm + (i*16 + l16)*40 + lg*8);
      #pragma unroll
      for (int i = 0; i < 4; i++)
        bf[i] = *(const bf16x8*)(b_sm + (w*64 + i*16 + l16)*40 + lg*8);
      #pragma unroll
      for (int mi = 0; mi < 4; mi++)
        #pragma unroll
        for (int ni = 0; ni < 4; ni++)
          acc[mi][ni] = mfma16(af[mi], bf[ni], acc[mi][ni]);
    }
  }
  u16* op = out + (size_t)blockIdx.y * M * 256;
  #pragma unroll
  for (int mi = 0; mi < 4; mi++)
    #pragma unroll
    for (int ni = 0; ni < 4; ni++)
      #pragma unroll
      for (int r = 0; r < 4; r++){
        int m = m0 + mi*16 + lg*4 + r;
        int n = w*64 + ni*16 + l16;
        op[(size_t)m*256 + n] = f2b(acc[mi][ni][r]);
      }
}

// ---------------- K-split partial reductions ----------------
// O[m][d] = (sum_z P[z][m][d]) / (sum_i lpart[i][m])   (l from QK col-block partials)
__global__ __launch_bounds__(256) void reduce_pv_k(const u16* __restrict__ P,
    const float* __restrict__ lpart, u16* __restrict__ O, int M, int ks, int nlp){
  __shared__ float lred[4];
  int m = blockIdx.x, d = threadIdx.x;
  int lane = d & 63, w = d >> 6;
  float la = 0.f;
  for (int i = d; i < nlp; i += 256) la += lpart[(size_t)i*M + m];
  #pragma unroll
  for (int off = 1; off < 64; off <<= 1) la += __shfl_xor(la, off, 64);
  if (lane == 0) lred[w] = la;
  __syncthreads();
  float l = lred[0] + lred[1] + lred[2] + lred[3];
  const size_t st = (size_t)M * 256;
  float s = 0.f;
  for (int i = 0; i < ks; i++) s += b2f(P[(size_t)i*st + (size_t)m*256 + d]);
  O[(size_t)m*256 + d] = f2b(s / l);
}
__global__ __launch_bounds__(256) void reduce_res_k(const u16* __restrict__ P,
    const float* __restrict__ bias, float* __restrict__ X, int M, int ks){
  int m = blockIdx.x, d = threadIdx.x;
  const size_t st = (size_t)M * 256;
  float s = bias[d];
  for (int i = 0; i < ks; i++) s += b2f(P[(size_t)i*st + (size_t)m*256 + d]);
  X[(size_t)m*256 + d] += s;
}

// ---------------- launch ----------------
extern "C" void kernel_launch(void* const* d_in, const int* in_sizes, int n_in,
                              void* d_out, int out_size, void* d_ws, size_t ws_size,
                              hipStream_t stream){
  (void)in_sizes; (void)n_in; (void)out_size;
  const float* curr       = (const float*)d_in[0];
  const float* memory     = (const float*)d_in[1];
  const float* curr_pos   = (const float*)d_in[2];
  const float* memory_pos = (const float*)d_in[3];
  const float* sa_w_qkv   = (const float*)d_in[4];
  const float* sa_b_qkv   = (const float*)d_in[5];
  const float* sa_w_o     = (const float*)d_in[6];
  const float* sa_b_o     = (const float*)d_in[7];
  const float* ca_w_qkv   = (const float*)d_in[8];
  const float* ca_b_qkv   = (const float*)d_in[9];
  const float* ca_w_o     = (const float*)d_in[10];
  const float* ca_b_o     = (const float*)d_in[11];
  const float* ln1_w = (const float*)d_in[12];
  const float* ln1_b = (const float*)d_in[13];
  const float* ln2_w = (const float*)d_in[14];
  const float* ln2_b = (const float*)d_in[15];
  const float* ln3_w = (const float*)d_in[16];
  const float* ln3_b = (const float*)d_in[17];
  const float* mlp_w1 = (const float*)d_in[18];
  const float* mlp_b1 = (const float*)d_in[19];
  const float* mlp_w2 = (const float*)d_in[20];
  const float* mlp_b2 = (const float*)d_in[21];
  const float* norm_w = (const float*)d_in[22];
  const float* norm_b = (const float*)d_in[23];

  char* wsp = (char*)d_ws;
  auto alloc = [&](size_t bytes)->void*{
    void* r = (void*)wsp; wsp += (bytes + 255) & ~(size_t)255; return r;
  };
  float* x     = (float*)alloc((size_t)SCUR*DM*4);
  u16*   t2b   = (u16*)  alloc((size_t)SCUR*DM*2);
  u16*   qkb   = (u16*)  alloc((size_t)SCUR*2*DM*2);
  u16*   vtsb  = (u16*)  alloc((size_t)DM*SCUR*2);
  u16*   Kb    = (u16*)  alloc((size_t)SMEM*DM*2);
  u16*   vtcb  = (u16*)  alloc((size_t)DM*SMEM*2);
  u16*   memkb = (u16*)  alloc((size_t)SMEM*DM*2);
  u16*   memb  = (u16*)  alloc((size_t)SMEM*DM*2);
  u16*   Hb    = (u16*)  alloc((size_t)SCUR*DFFN*2);
  u16*   Ppart = (u16*)  alloc((size_t)8*SCUR*DM*2);
  float* lpart = (float*)alloc((size_t)256*SCUR*4);   // QK col-block l partials (4MB)
  u16* wb_sa_qkv = (u16*)alloc((size_t)NL*3*DM*DM*2);
  u16* wb_sa_o   = (u16*)alloc((size_t)NL*DM*DM*2);
  u16* wb_ca_qkv = (u16*)alloc((size_t)NL*3*DM*DM*2);
  u16* wb_ca_o   = (u16*)alloc((size_t)NL*DM*DM*2);
  u16* wb_m1     = (u16*)alloc((size_t)NL*DFFN*DM*2);
  u16* wb_m2     = (u16*)alloc((size_t)NL*DM*DFFN*2);

  // ---- S/P buffer ----
  size_t used  = (size_t)(wsp - (char*)d_ws);
  size_t avail = (ws_size > used) ? (ws_size - used) : 0;
  const size_t rowb = (size_t)SMEM * 2;
  u16* Sbuf;
  int CHc;
  if (avail >= (size_t)SCUR * rowb){
    CHc = SCUR;
    Sbuf = (u16*)alloc((size_t)SCUR * rowb);
  } else {
    size_t ch = (avail / rowb) & ~(size_t)127;
    if (ch >= 512){
      CHc = (int)(ch > SCUR ? SCUR : ch);
      Sbuf = (u16*)alloc((size_t)CHc * rowb);
    } else {
      CHc = 512;
      Sbuf = Hb;
    }
  }
  size_t scap = (size_t)CHc * rowb;
  int CHs = (int)(scap / ((size_t)SCUR*2));
  if (CHs > SCUR) CHs = SCUR;
  CHs &= ~127;
  if (CHs < 128) CHs = 128;

  u16* PVc; int ksc;
  if (Sbuf != Hb){ PVc = Hb; ksc = 16; }
  else           { PVc = Ppart; ksc = 8; }

  u16* Ob = t2b;
  u16* Qb = qkb;

  const float* nullf = nullptr;
  float* nulll = nullptr;
  const float sc = 0.0625f;

  axpy_k<<<dim3(512), dim3(256), 0, stream>>>(curr, curr_pos, 0.1f, x, SCUR*DM/4);
  cvt_bf16_k<<<dim3(1024), dim3(256), 0, stream>>>(memory, memory_pos, memkb, SMEM*DM/4, 1.0f);
  cvt_bf16_k<<<dim3(1024), dim3(256), 0, stream>>>(memory, nullf, memb, SMEM*DM/4, 0.f);
  cvt_bf16_k<<<dim3(512), dim3(256), 0, stream>>>(sa_w_qkv, nullf, wb_sa_qkv, NL*3*DM*DM/4, 0.f);
  cvt_bf16_k<<<dim3(256), dim3(256), 0, stream>>>(sa_w_o,   nullf, wb_sa_o,   NL*DM*DM/4,   0.f);
  cvt_bf16_k<<<dim3(512), dim3(256), 0, stream>>>(ca_w_qkv, nullf, wb_ca_qkv, NL*3*DM*DM/4, 0.f);
  cvt_bf16_k<<<dim3(256), dim3(256), 0, stream>>>(ca_w_o,   nullf, wb_ca_o,   NL*DM*DM/4,   0.f);
  cvt_bf16_k<<<dim3(1024), dim3(256), 0, stream>>>(mlp_w1,  nullf, wb_m1,     NL*DFFN*DM/4, 0.f);
  cvt_bf16_k<<<dim3(1024), dim3(256), 0, stream>>>(mlp_w2,  nullf, wb_m2,     NL*DM*DFFN/4, 0.f);

  const dim3 blk(256);
  for (int l = 0; l < NL; l++){
    // ---- self attention ----
    ln_k<0><<<dim3(SCUR/4), blk, 0, stream>>>(x, ln1_w + l*DM, ln1_b + l*DM, (void*)t2b, SCUR);
    gemm_bt<0><<<dim3(512/64, SCUR/64), blk, 0, stream>>>(t2b, DM, wb_sa_qkv + (size_t)l*3*DM*DM, DM,
        sa_b_qkv + (size_t)l*3*DM, (void*)qkb, 512, SCUR, 512, DM);
    gemm_bt<3><<<dim3(SCUR/64, DM/64), blk, 0, stream>>>(wb_sa_qkv + ((size_t)l*3+2)*DM*DM, DM, t2b, DM,
        sa_b_qkv + (size_t)l*3*DM + 2*DM, (void*)vtsb, SCUR, DM, SCUR, DM);
    for (int c = 0; c < SCUR; c += CHs){
      int Mc = (SCUR - c) < CHs ? (SCUR - c) : CHs;
      gemm128<6><<<dim3(SCUR/128, Mc/128), blk, 0, stream>>>(qkb + (size_t)c*512, 512, qkb + DM, 512,
          nullf, (void*)Sbuf, SCUR, Mc, SCUR, DM, sc, lpart);
      gemm_pv<<<dim3(Mc/64, 8), blk, 0, stream>>>(Sbuf, SCUR, vtsb, SCUR, Ppart, Mc, SCUR/8);
      reduce_pv_k<<<dim3(Mc), blk, 0, stream>>>(Ppart, lpart, Ob + (size_t)c*DM, Mc, 8, (SCUR/128)*2);
    }
    gemm_bt<2><<<dim3(DM/64, SCUR/64), blk, 0, stream>>>(Ob, DM, wb_sa_o + (size_t)l*DM*DM, DM,
        sa_b_o + l*DM, (void*)x, DM, SCUR, DM, DM);

    // ---- cross attention ----
    ln_k<0><<<dim3(SCUR/4), blk, 0, stream>>>(x, ln2_w + l*DM, ln2_b + l*DM, (void*)t2b, SCUR);
    gemm_bt<0><<<dim3(DM/64, SCUR/64), blk, 0, stream>>>(t2b, DM, wb_ca_qkv + ((size_t)l*3+0)*DM*DM, DM,
        ca_b_qkv + l*3*DM + 0*DM, (void*)Qb, DM, SCUR, DM, DM);
    gemm_bt<0><<<dim3(DM/64, SMEM/64), blk, 0, stream>>>(memkb, DM, wb_ca_qkv + ((size_t)l*3+1)*DM*DM, DM,
        ca_b_qkv + l*3*DM + 1*DM, (void*)Kb, DM, SMEM, DM, DM);
    gemm_bt<3><<<dim3(SMEM/64, DM/64), blk, 0, stream>>>(wb_ca_qkv + ((size_t)l*3+2)*DM*DM, DM, memb, DM,
        ca_b_qkv + (size_t)l*3*DM + 2*DM, (void*)vtcb, SMEM, DM, SMEM, DM);
    for (int c = 0; c < SCUR; c += CHc){
      int Mc = (SCUR - c) < CHc ? (SCUR - c) : CHc;
      gemm128<6><<<dim3(SMEM/128, Mc/128), blk, 0, stream>>>(Qb + (size_t)c*DM, DM, Kb, DM,
          nullf, (void*)Sbuf, SMEM, Mc, SMEM, DM, sc, lpart);
      gemm_pv<<<dim3(Mc/64, ksc), blk, 0, stream>>>(Sbuf, SMEM, vtcb, SMEM, PVc, Mc, SMEM/ksc);
      reduce_pv_k<<<dim3(Mc), blk, 0, stream>>>(PVc, lpart, Ob + (size_t)c*DM, Mc, ksc, (SMEM/128)*2);
    }
    gemm_bt<2><<<dim3(DM/64, SCUR/64), blk, 0, stream>>>(Ob, DM, wb_ca_o + (size_t)l*DM*DM, DM,
        ca_b_o + l*DM, (void*)x, DM, SCUR, DM, DM);

    // ---- MLP ----
    ln_k<0><<<dim3(SCUR/4), blk, 0, stream>>>(x, ln3_w + l*DM, ln3_b + l*DM, (void*)t2b, SCUR);
    gemm128<1><<<dim3(DFFN/128, SCUR/128), blk, 0, stream>>>(t2b, DM, wb_m1 + (size_t)l*DFFN*DM, DM,
        mlp_b1 + l*DFFN, (void*)Hb, DFFN, SCUR, DFFN, DM, 0.f, nulll);
    gemm_pv<<<dim3(SCUR/64, 4), blk, 0, stream>>>(Hb, DFFN, wb_m2 + (size_t)l*DM*DFFN, DFFN,
        Ppart, SCUR, DFFN/4);
    reduce_res_k<<<dim3(SCUR), blk, 0, stream>>>(Ppart, mlp_b2 + l*DM, x, SCUR, 4);
  }

  ln_k<1><<<dim3(SCUR/4), blk, 0, stream>>>(x, norm_w, norm_b, d_out, SCUR);
}

// Round 18
// 1062.245 us; speedup vs baseline: 1.0581x; 1.0581x over previous
//
#include <hip/hip_runtime.h>
#include <hip/hip_bf16.h>

typedef unsigned short u16;
typedef unsigned int u32;
typedef __attribute__((ext_vector_type(8))) __bf16 bf16x8;
typedef __attribute__((ext_vector_type(4))) float f32x4;
typedef __attribute__((ext_vector_type(4))) u16 u16x4;
typedef __attribute__((ext_vector_type(8))) u16 u16x8;

#define SCUR 4096
#define SMEM 16384
#define DM   256
#define DFFN 2048
#define NL   4

__device__ __forceinline__ u16 f2b(float f){
  u32 i; __builtin_memcpy(&i, &f, 4);
  u32 r = (i + 0x7fffu + ((i >> 16) & 1u)) >> 16;
  return (u16)r;
}
__device__ __forceinline__ float b2f(u16 v){
  u32 i = ((u32)v) << 16; float f; __builtin_memcpy(&f, &i, 4); return f;
}

__device__ __forceinline__ f32x4 mfma16(bf16x8 a, bf16x8 b, f32x4 c){
  return __builtin_amdgcn_mfma_f32_16x16x32_bf16(a, b, c, 0, 0, 0);
}

__device__ __forceinline__ void glds16(const u16* g, u16* l){
  __builtin_amdgcn_global_load_lds(
      (const __attribute__((address_space(1))) u32*)g,
      (__attribute__((address_space(3))) u32*)l, 16, 0, 0);
}

// ---------------- elementwise prep ----------------

__global__ void axpy_k(const float* __restrict__ a, const float* __restrict__ b,
                       float s, float* __restrict__ o, int n4){
  int i = blockIdx.x * blockDim.x + threadIdx.x;
  int st = gridDim.x * blockDim.x;
  for (; i < n4; i += st){
    float4 x = ((const float4*)a)[i];
    float4 y = ((const float4*)b)[i];
    float4 r; r.x = x.x + s*y.x; r.y = x.y + s*y.y; r.z = x.z + s*y.z; r.w = x.w + s*y.w;
    ((float4*)o)[i] = r;
  }
}

__global__ void cvt_bf16_k(const float* __restrict__ a, const float* __restrict__ b,
                           u16* __restrict__ o, int n4, float s){
  int i = blockIdx.x * blockDim.x + threadIdx.x;
  int st = gridDim.x * blockDim.x;
  const bool hb = (b != nullptr);
  for (; i < n4; i += st){
    float4 x = ((const float4*)a)[i];
    if (hb){
      float4 y = ((const float4*)b)[i];
      x.x += s*y.x; x.y += s*y.y; x.z += s*y.z; x.w += s*y.w;
    }
    u16x4 r = { f2b(x.x), f2b(x.y), f2b(x.z), f2b(x.w) };
    ((u16x4*)o)[i] = r;
  }
}

// ---------------- layernorm ----------------
template<int OUTF32>
__global__ __launch_bounds__(256) void ln_k(const float* __restrict__ X,
    const float* __restrict__ g, const float* __restrict__ b,
    void* __restrict__ out, int rows){
  int row = blockIdx.x * 4 + (threadIdx.x >> 6);
  int lane = threadIdx.x & 63;
  if (row >= rows) return;
  const float4 v = *(const float4*)(X + (size_t)row*DM + lane*4);
  float s = v.x + v.y + v.z + v.w;
  for (int off = 1; off < 64; off <<= 1) s += __shfl_xor(s, off, 64);
  float mu = s * (1.f/256.f);
  float dx = v.x-mu, dy = v.y-mu, dz = v.z-mu, dw = v.w-mu;
  float q = dx*dx + dy*dy + dz*dz + dw*dw;
  for (int off = 1; off < 64; off <<= 1) q += __shfl_xor(q, off, 64);
  float rstd = rsqrtf(q * (1.f/256.f) + 1e-5f);
  const float4 gw = *(const float4*)(g + lane*4);
  const float4 gb = *(const float4*)(b + lane*4);
  float y0 = dx*rstd*gw.x + gb.x;
  float y1 = dy*rstd*gw.y + gb.y;
  float y2 = dz*rstd*gw.z + gb.z;
  float y3 = dw*rstd*gw.w + gb.w;
  if (OUTF32){
    float4 o; o.x=y0; o.y=y1; o.z=y2; o.w=y3;
    *(float4*)((float*)out + (size_t)row*DM + lane*4) = o;
  } else {
    u16x4 o = { f2b(y0), f2b(y1), f2b(y2), f2b(y3) };
    *(u16x4*)((u16*)out + (size_t)row*DM + lane*4) = o;
  }
}

// ---------------- 64-tile GEMM (small grids) ----------------
template<int EPI>
__global__ __launch_bounds__(256) void gemm_bt(
    const u16* __restrict__ A, int lda, const u16* __restrict__ W, int ldw,
    const float* __restrict__ bias, void* __restrict__ out, int ldc,
    int M, int N, int K){
  __shared__ u16 a_sm[64*40];
  __shared__ u16 b_sm[64*40];
  const int tid = threadIdx.x;
  const int lane = tid & 63;
  const int w = tid >> 6;
  const int l16 = lane & 15, lg = lane >> 4;
  const int m0 = blockIdx.y * 64;
  const int n0 = blockIdx.x * 64;
  const int wr = (w >> 1) * 32, wc = (w & 1) * 32;
  f32x4 acc[2][2] = {};
  const int srow = tid >> 2, sch = tid & 3;
  const u16* Ag = A + (size_t)(m0 + srow) * lda + sch * 8;
  const u16* Wg = W + (size_t)(n0 + srow) * ldw + sch * 8;
  u16x8 av = *(const u16x8*)(Ag);
  u16x8 wv = *(const u16x8*)(Wg);
  for (int k0 = 0; k0 < K; k0 += 32){
    __syncthreads();
    *(u16x8*)(a_sm + srow*40 + sch*8) = av;
    *(u16x8*)(b_sm + srow*40 + sch*8) = wv;
    if (k0 + 32 < K){
      av = *(const u16x8*)(Ag + k0 + 32);
      wv = *(const u16x8*)(Wg + k0 + 32);
    }
    __syncthreads();
    bf16x8 af0 = *(const bf16x8*)(a_sm + (wr      + l16)*40 + lg*8);
    bf16x8 af1 = *(const bf16x8*)(a_sm + (wr + 16 + l16)*40 + lg*8);
    bf16x8 bf0 = *(const bf16x8*)(b_sm + (wc      + l16)*40 + lg*8);
    bf16x8 bf1 = *(const bf16x8*)(b_sm + (wc + 16 + l16)*40 + lg*8);
    acc[0][0] = mfma16(af0, bf0, acc[0][0]);
    acc[0][1] = mfma16(af0, bf1, acc[0][1]);
    acc[1][0] = mfma16(af1, bf0, acc[1][0]);
    acc[1][1] = mfma16(af1, bf1, acc[1][1]);
  }
  for (int mi = 0; mi < 2; mi++)
    for (int ni = 0; ni < 2; ni++)
      for (int r = 0; r < 4; r++){
        int m = m0 + wr + mi*16 + lg*4 + r;
        int n = n0 + wc + ni*16 + l16;
        float v = acc[mi][ni][r];
        if (EPI == 3)      v += bias[m];
        else if (EPI != 4) v += bias[n];
        if (EPI == 2)      ((float*)out)[(size_t)m*ldc + n] += v;
        else if (EPI == 1) ((u16*)out)[(size_t)m*ldc + n] = f2b(v > 0.f ? v : 0.f);
        else               ((u16*)out)[(size_t)m*ldc + n] = f2b(v);
      }
}

// ---------------- 128x128-tile GEMM, double-buffered + counted vmcnt ----------------
// EPI: 1 relu->bf16+bias[n], 4 bf16 no bias
template<int EPI>
__global__ void gemm128(
    const u16* __restrict__ A, int lda, const u16* __restrict__ W, int ldw,
    const float* __restrict__ bias, void* __restrict__ out, int ldc,
    int M, int N, int K){
  __shared__ u16 a_sm[2][128*32];
  __shared__ u16 b_sm[2][128*32];
  const int tid = threadIdx.x, lane = tid & 63, w = tid >> 6;
  const int l16 = lane & 15, lg = lane >> 4;
  const int m0 = blockIdx.y * 128, n0 = blockIdx.x * 128;
  const int wr = (w >> 1) * 64, wc = (w & 1) * 64;
  f32x4 acc[4][4] = {};
  const int c0 = w*64 + lane, c1 = c0 + 256;
  const int r0 = c0 >> 2, cc0 = c0 & 3;
  const int r1 = c1 >> 2, cc1 = c1 & 3;
  const u16* Ag0 = A + (size_t)(m0 + r0)*lda + cc0*8;
  const u16* Ag1 = A + (size_t)(m0 + r1)*lda + cc1*8;
  const u16* Wg0 = W + (size_t)(n0 + r0)*ldw + cc0*8;
  const u16* Wg1 = W + (size_t)(n0 + r1)*ldw + cc1*8;
  const int nk = K >> 5;
  glds16(Ag0, a_sm[0] + w*512);
  glds16(Ag1, a_sm[0] + w*512 + 2048);
  glds16(Wg0, b_sm[0] + w*512);
  glds16(Wg1, b_sm[0] + w*512 + 2048);
  __builtin_amdgcn_sched_barrier(0);
  for (int k = 0; k < nk; k++){
    const int cur = k & 1;
    if (k + 1 < nk){
      const int nxt = cur ^ 1;
      const int ko = (k + 1) * 32;
      glds16(Ag0 + ko, a_sm[nxt] + w*512);
      glds16(Ag1 + ko, a_sm[nxt] + w*512 + 2048);
      glds16(Wg0 + ko, b_sm[nxt] + w*512);
      glds16(Wg1 + ko, b_sm[nxt] + w*512 + 2048);
      __builtin_amdgcn_sched_barrier(0);
      asm volatile("s_waitcnt vmcnt(4)" ::: "memory");
    } else {
      asm volatile("s_waitcnt vmcnt(0)" ::: "memory");
    }
    __builtin_amdgcn_s_barrier();
    bf16x8 af[4], bf[4];
    #pragma unroll
    for (int mi = 0; mi < 4; mi++)
      af[mi] = *(const bf16x8*)(a_sm[cur] + (wr + mi*16 + l16)*32 + lg*8);
    #pragma unroll
    for (int ni = 0; ni < 4; ni++)
      bf[ni] = *(const bf16x8*)(b_sm[cur] + (wc + ni*16 + l16)*32 + lg*8);
    #pragma unroll
    for (int mi = 0; mi < 4; mi++)
      #pragma unroll
      for (int ni = 0; ni < 4; ni++)
        acc[mi][ni] = mfma16(af[mi], bf[ni], acc[mi][ni]);
    __builtin_amdgcn_s_barrier();
  }
  #pragma unroll
  for (int mi = 0; mi < 4; mi++)
    #pragma unroll
    for (int ni = 0; ni < 4; ni++)
      #pragma unroll
      for (int r = 0; r < 4; r++){
        int m = m0 + wr + mi*16 + lg*4 + r;
        int n = n0 + wc + ni*16 + l16;
        float v = acc[mi][ni][r];
        if (EPI == 1){
          v += bias[n];
          ((u16*)out)[(size_t)m*ldc + n] = f2b(v > 0.f ? v : 0.f);
        } else {
          ((u16*)out)[(size_t)m*ldc + n] = f2b(v);
        }
      }
}

// ---------------- wide-N GEMM for PV / down-proj (BM=64, N=256, 2-deep prefetch) ----------------
// EXPA=1: one-pass softmax numerator p=exp(s*scale), exp computed in the MFMA
// shadow of the previous sub-step; lpart[z][m] row sums. K divisible by 64.
template<int EXPA>
__global__ __launch_bounds__(256) void gemm_pv(
    const u16* __restrict__ A, int lda, const u16* __restrict__ W, int ldw,
    u16* __restrict__ out, int M, int K,
    float* __restrict__ lpart, float scale){
  __shared__ u16 a_sm[64*40];
  __shared__ u16 b_sm[256*40];
  const int tid = threadIdx.x, lane = tid & 63, w = tid >> 6;
  const int l16 = lane & 15, lg = lane >> 4;
  const int m0 = blockIdx.x * 64;
  const int koff = blockIdx.y * K;
  f32x4 acc[4][4] = {};
  const int srow = tid >> 2, sch = tid & 3;
  float lsum = 0.f;
  const u16* Ag = A + (size_t)(m0 + srow) * lda + sch * 8 + koff;
  const u16* Wg = W + (size_t)srow * ldw + sch * 8 + koff;
  u16x8 avX = *(const u16x8*)(Ag);
  u16x8 wv0X = *(const u16x8*)(Wg);
  u16x8 wv1X = *(const u16x8*)(Wg + (size_t)64*ldw);
  u16x8 wv2X = *(const u16x8*)(Wg + (size_t)128*ldw);
  u16x8 wv3X = *(const u16x8*)(Wg + (size_t)192*ldw);
  u16x8 avY = *(const u16x8*)(Ag + 32);
  u16x8 wv0Y = *(const u16x8*)(Wg + 32);
  u16x8 wv1Y = *(const u16x8*)(Wg + (size_t)64*ldw + 32);
  u16x8 wv2Y = *(const u16x8*)(Wg + (size_t)128*ldw + 32);
  u16x8 wv3Y = *(const u16x8*)(Wg + (size_t)192*ldw + 32);
  // prologue transform for X (waits on first load only)
  u16x8 asX, asY;
  if (EXPA){
    #pragma unroll
    for (int e = 0; e < 8; e++){
      float p = __expf(b2f(avX[e]) * scale);
      lsum += p;
      asX[e] = f2b(p);
    }
  }
  for (int k0 = 0; k0 < K; k0 += 64){
    __syncthreads();
    *(u16x8*)(a_sm + srow*40 + sch*8) = EXPA ? asX : avX;
    *(u16x8*)(b_sm + srow*40 + sch*8) = wv0X;
    *(u16x8*)(b_sm + (srow+64)*40 + sch*8) = wv1X;
    *(u16x8*)(b_sm + (srow+128)*40 + sch*8) = wv2X;
    *(u16x8*)(b_sm + (srow+192)*40 + sch*8) = wv3X;
    if (k0 + 64 < K){
      avX  = *(const u16x8*)(Ag + k0 + 64);
      wv0X = *(const u16x8*)(Wg + k0 + 64);
      wv1X = *(const u16x8*)(Wg + (size_t)64*ldw + k0 + 64);
      wv2X = *(const u16x8*)(Wg + (size_t)128*ldw + k0 + 64);
      wv3X = *(const u16x8*)(Wg + (size_t)192*ldw + k0 + 64);
    }
    __syncthreads();
    {
      bf16x8 af[4], bf[4];
      #pragma unroll
      for (int i = 0; i < 4; i++)
        af[i] = *(const bf16x8*)(a_sm + (i*16 + l16)*40 + lg*8);
      #pragma unroll
      for (int i = 0; i < 4; i++)
        bf[i] = *(const bf16x8*)(b_sm + (w*64 + i*16 + l16)*40 + lg*8);
      #pragma unroll
      for (int mi = 0; mi < 4; mi++)
        #pragma unroll
        for (int ni = 0; ni < 4; ni++)
          acc[mi][ni] = mfma16(af[mi], bf[ni], acc[mi][ni]);
    }
    // exp for Y in the MFMA-X shadow (avY landed >=1 phase ago)
    if (EXPA){
      #pragma unroll
      for (int e = 0; e < 8; e++){
        float p = __expf(b2f(avY[e]) * scale);
        lsum += p;
        asY[e] = f2b(p);
      }
    }
    __syncthreads();
    *(u16x8*)(a_sm + srow*40 + sch*8) = EXPA ? asY : avY;
    *(u16x8*)(b_sm + srow*40 + sch*8) = wv0Y;
    *(u16x8*)(b_sm + (srow+64)*40 + sch*8) = wv1Y;
    *(u16x8*)(b_sm + (srow+128)*40 + sch*8) = wv2Y;
    *(u16x8*)(b_sm + (srow+192)*40 + sch*8) = wv3Y;
    if (k0 + 96 < K){
      avY  = *(const u16x8*)(Ag + k0 + 96);
      wv0Y = *(const u16x8*)(Wg + k0 + 96);
      wv1Y = *(const u16x8*)(Wg + (size_t)64*ldw + k0 + 96);
      wv2Y = *(const u16x8*)(Wg + (size_t)128*ldw + k0 + 96);
      wv3Y = *(const u16x8*)(Wg + (size_t)192*ldw + k0 + 96);
    }
    __syncthreads();
    {
      bf16x8 af[4], bf[4];
      #pragma unroll
      for (int i = 0; i < 4; i++)
        af[i] = *(const bf16x8*)(a_sm + (i*16 + l16)*40 + lg*8);
      #pragma unroll
      for (int i = 0; i < 4; i++)
        bf[i] = *(const bf16x8*)(b_sm + (w*64 + i*16 + l16)*40 + lg*8);
      #pragma unroll
      for (int mi = 0; mi < 4; mi++)
        #pragma unroll
        for (int ni = 0; ni < 4; ni++)
          acc[mi][ni] = mfma16(af[mi], bf[ni], acc[mi][ni]);
    }
    // exp for next X in the MFMA-Y shadow (avX issued one full phase ago)
    if (EXPA && k0 + 64 < K){
      #pragma unroll
      for (int e = 0; e < 8; e++){
        float p = __expf(b2f(avX[e]) * scale);
        lsum += p;
        asX[e] = f2b(p);
      }
    }
  }
  if (EXPA){
    lsum += __shfl_xor(lsum, 1, 64);
    lsum += __shfl_xor(lsum, 2, 64);
    if (sch == 0) lpart[(size_t)blockIdx.y * M + m0 + srow] = lsum;
  }
  u16* op = out + (size_t)blockIdx.y * M * 256;
  #pragma unroll
  for (int mi = 0; mi < 4; mi++)
    #pragma unroll
    for (int ni = 0; ni < 4; ni++)
      #pragma unroll
      for (int r = 0; r < 4; r++){
        int m = m0 + mi*16 + lg*4 + r;
        int n = w*64 + ni*16 + l16;
        op[(size_t)m*256 + n] = f2b(acc[mi][ni][r]);
      }
}

// ---------------- K-split partial reductions ----------------
__global__ __launch_bounds__(256) void reduce_pv_k(const u16* __restrict__ P,
    const float* __restrict__ lpart, u16* __restrict__ O, int M, int ks){
  int m = blockIdx.x, d = threadIdx.x;
  const size_t st = (size_t)M * 256;
  float s = 0.f, l = 0.f;
  for (int i = 0; i < ks; i++){
    s += b2f(P[(size_t)i*st + (size_t)m*256 + d]);
    l += lpart[(size_t)i*M + m];
  }
  O[(size_t)m*256 + d] = f2b(s / l);
}
__global__ __launch_bounds__(256) void reduce_res_k(const u16* __restrict__ P,
    const float* __restrict__ bias, float* __restrict__ X, int M, int ks){
  int m = blockIdx.x, d = threadIdx.x;
  const size_t st = (size_t)M * 256;
  float s = bias[d];
  for (int i = 0; i < ks; i++) s += b2f(P[(size_t)i*st + (size_t)m*256 + d]);
  X[(size_t)m*256 + d] += s;
}

// ---------------- launch ----------------
extern "C" void kernel_launch(void* const* d_in, const int* in_sizes, int n_in,
                              void* d_out, int out_size, void* d_ws, size_t ws_size,
                              hipStream_t stream){
  (void)in_sizes; (void)n_in; (void)out_size;
  const float* curr       = (const float*)d_in[0];
  const float* memory     = (const float*)d_in[1];
  const float* curr_pos   = (const float*)d_in[2];
  const float* memory_pos = (const float*)d_in[3];
  const float* sa_w_qkv   = (const float*)d_in[4];
  const float* sa_b_qkv   = (const float*)d_in[5];
  const float* sa_w_o     = (const float*)d_in[6];
  const float* sa_b_o     = (const float*)d_in[7];
  const float* ca_w_qkv   = (const float*)d_in[8];
  const float* ca_b_qkv   = (const float*)d_in[9];
  const float* ca_w_o     = (const float*)d_in[10];
  const float* ca_b_o     = (const float*)d_in[11];
  const float* ln1_w = (const float*)d_in[12];
  const float* ln1_b = (const float*)d_in[13];
  const float* ln2_w = (const float*)d_in[14];
  const float* ln2_b = (const float*)d_in[15];
  const float* ln3_w = (const float*)d_in[16];
  const float* ln3_b = (const float*)d_in[17];
  const float* mlp_w1 = (const float*)d_in[18];
  const float* mlp_b1 = (const float*)d_in[19];
  const float* mlp_w2 = (const float*)d_in[20];
  const float* mlp_b2 = (const float*)d_in[21];
  const float* norm_w = (const float*)d_in[22];
  const float* norm_b = (const float*)d_in[23];

  char* wsp = (char*)d_ws;
  auto alloc = [&](size_t bytes)->void*{
    void* r = (void*)wsp; wsp += (bytes + 255) & ~(size_t)255; return r;
  };
  float* x     = (float*)alloc((size_t)SCUR*DM*4);
  u16*   t2b   = (u16*)  alloc((size_t)SCUR*DM*2);
  u16*   qkb   = (u16*)  alloc((size_t)SCUR*2*DM*2);
  u16*   vtsb  = (u16*)  alloc((size_t)DM*SCUR*2);
  u16*   Kb    = (u16*)  alloc((size_t)SMEM*DM*2);
  u16*   vtcb  = (u16*)  alloc((size_t)DM*SMEM*2);
  u16*   memkb = (u16*)  alloc((size_t)SMEM*DM*2);
  u16*   memb  = (u16*)  alloc((size_t)SMEM*DM*2);
  u16*   Hb    = (u16*)  alloc((size_t)SCUR*DFFN*2);
  u16*   Ppart = (u16*)  alloc((size_t)8*SCUR*DM*2);
  float* lpart = (float*)alloc((size_t)16*SCUR*4);
  u16* wb_sa_qkv = (u16*)alloc((size_t)NL*3*DM*DM*2);
  u16* wb_sa_o   = (u16*)alloc((size_t)NL*DM*DM*2);
  u16* wb_ca_qkv = (u16*)alloc((size_t)NL*3*DM*DM*2);
  u16* wb_ca_o   = (u16*)alloc((size_t)NL*DM*DM*2);
  u16* wb_m1     = (u16*)alloc((size_t)NL*DFFN*DM*2);
  u16* wb_m2     = (u16*)alloc((size_t)NL*DM*DFFN*2);

  // ---- S buffer ----
  size_t used  = (size_t)(wsp - (char*)d_ws);
  size_t avail = (ws_size > used) ? (ws_size - used) : 0;
  const size_t rowb = (size_t)SMEM * 2;
  u16* Sbuf;
  int CHc;
  if (avail >= (size_t)SCUR * rowb){
    CHc = SCUR;
    Sbuf = (u16*)alloc((size_t)SCUR * rowb);
  } else {
    size_t ch = (avail / rowb) & ~(size_t)127;
    if (ch >= 512){
      CHc = (int)(ch > SCUR ? SCUR : ch);
      Sbuf = (u16*)alloc((size_t)CHc * rowb);
    } else {
      CHc = 512;
      Sbuf = Hb;
    }
  }
  size_t scap = (size_t)CHc * rowb;
  int CHs = (int)(scap / ((size_t)SCUR*2));
  if (CHs > SCUR) CHs = SCUR;
  CHs &= ~127;
  if (CHs < 128) CHs = 128;

  u16* PVc; int ksc;
  if (Sbuf != Hb){ PVc = Hb; ksc = 16; }
  else           { PVc = Ppart; ksc = 8; }

  u16* Ob = t2b;
  u16* Qb = qkb;

  const float* nullf = nullptr;
  float* nulll = nullptr;
  const float sc = 0.0625f;

  axpy_k<<<dim3(512), dim3(256), 0, stream>>>(curr, curr_pos, 0.1f, x, SCUR*DM/4);
  cvt_bf16_k<<<dim3(1024), dim3(256), 0, stream>>>(memory, memory_pos, memkb, SMEM*DM/4, 1.0f);
  cvt_bf16_k<<<dim3(1024), dim3(256), 0, stream>>>(memory, nullf, memb, SMEM*DM/4, 0.f);
  cvt_bf16_k<<<dim3(512), dim3(256), 0, stream>>>(sa_w_qkv, nullf, wb_sa_qkv, NL*3*DM*DM/4, 0.f);
  cvt_bf16_k<<<dim3(256), dim3(256), 0, stream>>>(sa_w_o,   nullf, wb_sa_o,   NL*DM*DM/4,   0.f);
  cvt_bf16_k<<<dim3(512), dim3(256), 0, stream>>>(ca_w_qkv, nullf, wb_ca_qkv, NL*3*DM*DM/4, 0.f);
  cvt_bf16_k<<<dim3(256), dim3(256), 0, stream>>>(ca_w_o,   nullf, wb_ca_o,   NL*DM*DM/4,   0.f);
  cvt_bf16_k<<<dim3(1024), dim3(256), 0, stream>>>(mlp_w1,  nullf, wb_m1,     NL*DFFN*DM/4, 0.f);
  cvt_bf16_k<<<dim3(1024), dim3(256), 0, stream>>>(mlp_w2,  nullf, wb_m2,     NL*DM*DFFN/4, 0.f);

  const dim3 blk(256);
  for (int l = 0; l < NL; l++){
    // ---- self attention ----
    ln_k<0><<<dim3(SCUR/4), blk, 0, stream>>>(x, ln1_w + l*DM, ln1_b + l*DM, (void*)t2b, SCUR);
    gemm_bt<0><<<dim3(512/64, SCUR/64), blk, 0, stream>>>(t2b, DM, wb_sa_qkv + (size_t)l*3*DM*DM, DM,
        sa_b_qkv + (size_t)l*3*DM, (void*)qkb, 512, SCUR, 512, DM);
    gemm_bt<3><<<dim3(SCUR/64, DM/64), blk, 0, stream>>>(wb_sa_qkv + ((size_t)l*3+2)*DM*DM, DM, t2b, DM,
        sa_b_qkv + (size_t)l*3*DM + 2*DM, (void*)vtsb, SCUR, DM, SCUR, DM);
    for (int c = 0; c < SCUR; c += CHs){
      int Mc = (SCUR - c) < CHs ? (SCUR - c) : CHs;
      gemm128<4><<<dim3(SCUR/128, Mc/128), blk, 0, stream>>>(qkb + (size_t)c*512, 512, qkb + DM, 512,
          nullf, (void*)Sbuf, SCUR, Mc, SCUR, DM);
      gemm_pv<1><<<dim3(Mc/64, 8), blk, 0, stream>>>(Sbuf, SCUR, vtsb, SCUR,
          Ppart, Mc, SCUR/8, lpart, sc);
      reduce_pv_k<<<dim3(Mc), blk, 0, stream>>>(Ppart, lpart, Ob + (size_t)c*DM, Mc, 8);
    }
    gemm_bt<2><<<dim3(DM/64, SCUR/64), blk, 0, stream>>>(Ob, DM, wb_sa_o + (size_t)l*DM*DM, DM,
        sa_b_o + l*DM, (void*)x, DM, SCUR, DM, DM);

    // ---- cross attention ----
    ln_k<0><<<dim3(SCUR/4), blk, 0, stream>>>(x, ln2_w + l*DM, ln2_b + l*DM, (void*)t2b, SCUR);
    gemm_bt<0><<<dim3(DM/64, SCUR/64), blk, 0, stream>>>(t2b, DM, wb_ca_qkv + ((size_t)l*3+0)*DM*DM, DM,
        ca_b_qkv + l*3*DM + 0*DM, (void*)Qb, DM, SCUR, DM, DM);
    gemm_bt<0><<<dim3(DM/64, SMEM/64), blk, 0, stream>>>(memkb, DM, wb_ca_qkv + ((size_t)l*3+1)*DM*DM, DM,
        ca_b_qkv + l*3*DM + 1*DM, (void*)Kb, DM, SMEM, DM, DM);
    gemm_bt<3><<<dim3(SMEM/64, DM/64), blk, 0, stream>>>(wb_ca_qkv + ((size_t)l*3+2)*DM*DM, DM, memb, DM,
        ca_b_qkv + (size_t)l*3*DM + 2*DM, (void*)vtcb, SMEM, DM, SMEM, DM);
    for (int c = 0; c < SCUR; c += CHc){
      int Mc = (SCUR - c) < CHc ? (SCUR - c) : CHc;
      gemm128<4><<<dim3(SMEM/128, Mc/128), blk, 0, stream>>>(Qb + (size_t)c*DM, DM, Kb, DM,
          nullf, (void*)Sbuf, SMEM, Mc, SMEM, DM);
      gemm_pv<1><<<dim3(Mc/64, ksc), blk, 0, stream>>>(Sbuf, SMEM, vtcb, SMEM,
          PVc, Mc, SMEM/ksc, lpart, sc);
      reduce_pv_k<<<dim3(Mc), blk, 0, stream>>>(PVc, lpart, Ob + (size_t)c*DM, Mc, ksc);
    }
    gemm_bt<2><<<dim3(DM/64, SCUR/64), blk, 0, stream>>>(Ob, DM, wb_ca_o + (size_t)l*DM*DM, DM,
        ca_b_o + l*DM, (void*)x, DM, SCUR, DM, DM);

    // ---- MLP ----
    ln_k<0><<<dim3(SCUR/4), blk, 0, stream>>>(x, ln3_w + l*DM, ln3_b + l*DM, (void*)t2b, SCUR);
    gemm128<1><<<dim3(DFFN/128, SCUR/128), blk, 0, stream>>>(t2b, DM, wb_m1 + (size_t)l*DFFN*DM, DM,
        mlp_b1 + l*DFFN, (void*)Hb, DFFN, SCUR, DFFN, DM);
    gemm_pv<0><<<dim3(SCUR/64, 4), blk, 0, stream>>>(Hb, DFFN, wb_m2 + (size_t)l*DM*DFFN, DFFN,
        Ppart, SCUR, DFFN/4, nulll, 0.f);
    reduce_res_k<<<dim3(SCUR), blk, 0, stream>>>(Ppart, mlp_b2 + l*DM, x, SCUR, 4);
  }

  ln_k<1><<<dim3(SCUR/4), blk, 0, stream>>>(x, norm_w, norm_b, d_out, SCUR);
}